// Round 5
// baseline (720.524 us; speedup 1.0000x reference)
//
#include <hip/hip_runtime.h>

#define BSZ   128
#define CC    2048
#define HW    196
#define NDESC 32
#define NANS  1845

#define TROWS  16                               // A-rows per gemm block
#define ATILES ((NANS + TROWS - 1) / TROWS)     // 116
#define GRID2  (NDESC * ATILES)                 // 3712 (divisible by 8)

typedef float f4 __attribute__((ext_vector_type(4)));

// ---------------------------------------------------------------------------
// Kernel A: attended[b][c] = (1/196) * sum_hw mask[b][hw] * feat[b][c][hw]
// 4 waves/block, each wave owns 4 consecutive rows: 4 independent 784 B
// loads in flight per wave (latency hiding: 1 load/wave was ~7 B/cy/CU,
// under the ~10 B/cy needed for HBM peak). 2048 % 16 == 0 so a block never
// crosses a batch boundary. Block 0 additionally builds the grouping lists.
// ---------------------------------------------------------------------------
__global__ __launch_bounds__(256) void attend_group_kernel(
        const float* __restrict__ mask,
        const float* __restrict__ feat,
        const int*  __restrict__ inst,
        float* __restrict__ attended,
        int* __restrict__ counts,
        int* __restrict__ lists) {
    int wave = threadIdx.x >> 6;
    int lane = threadIdx.x & 63;
    int row0 = blockIdx.x * 16 + wave * 4;            // 4 consecutive rows
    int b    = row0 >> 11;                            // CC = 2048

    f4 m = {0.f, 0.f, 0.f, 0.f};
    if (lane < 49) m = ((const f4*)(mask + (size_t)b * HW))[lane];

    // rows are contiguous: row r starts at f4-index r*49 (784 B, 16B-aligned)
    const f4* fr = (const f4*)(feat + (size_t)row0 * HW);
    float p[4] = {0.f, 0.f, 0.f, 0.f};
    if (lane < 49) {
        f4 f0 = fr[0 * 49 + lane];
        f4 f1 = fr[1 * 49 + lane];
        f4 f2 = fr[2 * 49 + lane];
        f4 f3 = fr[3 * 49 + lane];
        p[0] = f0.x * m.x + f0.y * m.y + f0.z * m.z + f0.w * m.w;
        p[1] = f1.x * m.x + f1.y * m.y + f1.z * m.z + f1.w * m.w;
        p[2] = f2.x * m.x + f2.y * m.y + f2.z * m.z + f2.w * m.w;
        p[3] = f3.x * m.x + f3.y * m.y + f3.z * m.z + f3.w * m.w;
    }
    #pragma unroll
    for (int off = 32; off; off >>= 1) {
        p[0] += __shfl_xor(p[0], off, 64);
        p[1] += __shfl_xor(p[1], off, 64);
        p[2] += __shfl_xor(p[2], off, 64);
        p[3] += __shfl_xor(p[3], off, 64);
    }
    if (lane == 0) {
        attended[row0 + 0] = p[0] * (1.f / 196.f);
        attended[row0 + 1] = p[1] * (1.f / 196.f);
        attended[row0 + 2] = p[2] * (1.f / 196.f);
        attended[row0 + 3] = p[3] * (1.f / 196.f);
    }

    if (blockIdx.x == 0) {                            // block-uniform branch
        int t = threadIdx.x;
        if (t < NDESC) counts[t] = 0;
        __syncthreads();
        if (t < BSZ) {
            int i = inst[t];
            int slot = atomicAdd(&counts[i], 1);
            lists[i * BSZ + slot] = t;
        }
    }
}

// ---------------------------------------------------------------------------
// Kernel B: grouped GEMM. 3712 blocks (XCD-chunked), 512 threads = 8 waves
// x 2 A-rows. W rows in registers (64 VGPR, read exactly once, nt loads).
// attended rows LDS-staged once per member (double buffer, one barrier).
// __launch_bounds__(512,4): 4 waves/EU -> VGPR<=128 -> 2 blocks/CU so the
// co-resident block's compute overlaps this block's W stream.
// ---------------------------------------------------------------------------
__global__ __launch_bounds__(512, 4) void gemm_kernel(
        const float* __restrict__ attended,
        const float* __restrict__ W,
        const float* __restrict__ bias,
        const int* __restrict__ counts,
        const int* __restrict__ lists,
        float* __restrict__ out) {
    int bid     = blockIdx.x;
    int logical = (bid & 7) * (GRID2 / 8) + (bid >> 3);   // bijective: 3712%8==0
    int ins     = logical / ATILES;
    int tile    = logical % ATILES;
    int cnt     = counts[ins];
    if (cnt == 0) return;                 // unused instance: skip W entirely

    int tid  = threadIdx.x;
    int wid  = tid >> 6;
    int lane = tid & 63;
    int a0   = tile * TROWS + wid * 2;
    int a1   = a0 + 1;
    bool v0  = a0 < NANS;
    bool v1  = a1 < NANS;

    const float* Wb = W + (size_t)ins * NANS * CC;

    f4 w0[8], w1[8];
    if (v0) {
        const f4* wr = (const f4*)(Wb + (size_t)a0 * CC) + lane;
        #pragma unroll
        for (int k = 0; k < 8; ++k) w0[k] = __builtin_nontemporal_load(wr + k * 64);
    }
    if (v1) {
        const f4* wr = (const f4*)(Wb + (size_t)a1 * CC) + lane;
        #pragma unroll
        for (int k = 0; k < 8; ++k) w1[k] = __builtin_nontemporal_load(wr + k * 64);
    }
    float b0 = v0 ? bias[ins * NANS + a0] : 0.f;
    float b1 = v1 ? bias[ins * NANS + a1] : 0.f;

    __shared__ float lds[2][CC];          // 16 KiB double buffer
    const int* lst = lists + ins * BSZ;

    f4 stage = *((const f4*)(attended + (size_t)lst[0] * CC) + tid);

    for (int j = 0; j < cnt; ++j) {
        int buf = j & 1;
        ((f4*)lds[buf])[tid] = stage;
        if (j + 1 < cnt)
            stage = *((const f4*)(attended + (size_t)lst[j + 1] * CC) + tid);
        __syncthreads();

        float acc0 = 0.f, acc1 = 0.f;
        #pragma unroll
        for (int k = 0; k < 8; ++k) {
            f4 x = ((const f4*)lds[buf])[lane + k * 64];
            acc0 += x.x * w0[k].x + x.y * w0[k].y + x.z * w0[k].z + x.w * w0[k].w;
            acc1 += x.x * w1[k].x + x.y * w1[k].y + x.z * w1[k].z + x.w * w1[k].w;
        }
        #pragma unroll
        for (int off = 32; off; off >>= 1) {
            acc0 += __shfl_xor(acc0, off, 64);
            acc1 += __shfl_xor(acc1, off, 64);
        }
        if (lane == 0) {
            int bj = lst[j];
            if (v0) out[(size_t)bj * NANS + a0] = acc0 + b0;
            if (v1) out[(size_t)bj * NANS + a1] = acc1 + b1;
        }
    }
}

// ---------------------------------------------------------------------------
extern "C" void kernel_launch(void* const* d_in, const int* in_sizes, int n_in,
                              void* d_out, int out_size, void* d_ws, size_t ws_size,
                              hipStream_t stream) {
    const float* mask = (const float*)d_in[0];   // [128,1,14,14]
    const float* feat = (const float*)d_in[1];   // [128,2048,14,14]
    const int*   inst = (const int*)d_in[2];     // [128]
    const float* W    = (const float*)d_in[3];   // [32,1845,2048]
    const float* bias = (const float*)d_in[4];   // [32,1845]
    float*       out  = (float*)d_out;           // [128,1845]

    float* attended = (float*)d_ws;                                   // 1 MB
    int*   counts   = (int*)((char*)d_ws + (size_t)BSZ * CC * sizeof(float));
    int*   lists    = counts + NDESC;                                 // 32*128

    attend_group_kernel<<<(BSZ * CC) / 16, 256, 0, stream>>>(
        mask, feat, inst, attended, counts, lists);
    gemm_kernel<<<GRID2, 512, 0, stream>>>(
        attended, W, bias, counts, lists, out);
}